// Round 10
// baseline (299.592 us; speedup 1.0000x reference)
//
#include <hip/hip_runtime.h>
#include <hip/hip_bf16.h>

// CffmTransformerBlock3d3 — round 10 (= r9 + swapped-operand GEMM epilogue).
//  * GEMM : acc = mfma(B_frag, A_frag) so each lane owns 4 consecutive N
//           values -> 8B (bf16) / 16B (fp32) vector C-stores, 16 instead of
//           64 scalar stores per thread. Math identical.
//  * attn : unchanged from r9 (XCD-chunked, 62MB FETCH, ~98us).

#define NKEYS 377

typedef unsigned int u32;
typedef unsigned short u16;
typedef __attribute__((ext_vector_type(8))) short bf16x8;
typedef __attribute__((ext_vector_type(8))) unsigned short u16x8;
typedef __attribute__((ext_vector_type(4))) unsigned int u32x4;
typedef __attribute__((ext_vector_type(2))) unsigned int u32x2;
typedef __attribute__((ext_vector_type(4))) float f32x4;

__device__ __forceinline__ u16 f2bf(float f) {
    u32 b = __float_as_uint(f);
    b += 0x7FFFu + ((b >> 16) & 1u);
    return (u16)(b >> 16);
}
__device__ __forceinline__ u32 pack2(float lo, float hi) {
    return (u32)f2bf(lo) | ((u32)f2bf(hi) << 16);
}
__device__ __forceinline__ bf16x8 cvt8(float4 x, float4 y) {
    union { bf16x8 v; __hip_bfloat162 h[4]; } un;
    un.h[0] = __float22bfloat162_rn(make_float2(x.x, x.y));
    un.h[1] = __float22bfloat162_rn(make_float2(x.z, x.w));
    un.h[2] = __float22bfloat162_rn(make_float2(y.x, y.y));
    un.h[3] = __float22bfloat162_rn(make_float2(y.z, y.w));
    return un.v;
}

// ---------------- fp32 -> bf16 conversion (grid-stride, 8 elems/thread) ----
__global__ __launch_bounds__(256)
void cvt_kernel(const float* __restrict__ x,  const float* __restrict__ c1,
                const float* __restrict__ c2, const float* __restrict__ c3,
                const float* __restrict__ p0,
                __hip_bfloat16* __restrict__ xb, __hip_bfloat16* __restrict__ c1b,
                __hip_bfloat16* __restrict__ c2b, __hip_bfloat16* __restrict__ c3b,
                __hip_bfloat16* __restrict__ p0b)
{
    const int U0 = 802816, U1 = 1605632, U2 = 2015232, U3 = 2162688, U4 = 2965504;
    for (int u = blockIdx.x * 256 + threadIdx.x; u < U4; u += gridDim.x * 256) {
        const float* s; __hip_bfloat16* d; int o;
        if (u < U0)      { s = x;  d = xb;  o = u; }
        else if (u < U1) { s = c1; d = c1b; o = u - U0; }
        else if (u < U2) { s = c2; d = c2b; o = u - U1; }
        else if (u < U3) { s = c3; d = c3b; o = u - U2; }
        else             { s = p0; d = p0b; o = u - U3; }
        const float4 a = *(const float4*)(s + (size_t)o * 8);
        const float4 b = *(const float4*)(s + (size_t)o * 8 + 4);
        *(bf16x8*)((short*)d + (size_t)o * 8) = cvt8(a, b);
    }
}

// ---------------- weight prep: Wt[n][k] = bf16(W[k][n]) ----------------
__global__ __launch_bounds__(256)
void wprep_kernel(const float* __restrict__ qkv_w,   // [256][768]
                  const float* __restrict__ proj_w,  // [256][256]
                  __hip_bfloat16* __restrict__ wq,   // [768][256]
                  __hip_bfloat16* __restrict__ wp)   // [256][256]
{
    const int n = blockIdx.x;
    const int k = threadIdx.x;
    if (n < 768) wq[n * 256 + k] = __float2bfloat16(qkv_w[k * 768 + n]);
    else         wp[(n - 768) * 256 + k] = __float2bfloat16(proj_w[k * 256 + (n - 768)]);
}

// ---------------- bf16 MFMA GEMM (m97-style, XCD-swizzled 1D grid) ----------
// A[M][256] bf16, Bt[N][256] bf16 (K-contig), C + bias (bf16 or fp32 out).
// 128x128 tile, 4 waves, K-tiles of 32, global_load_lds + double buffer,
// ONE barrier per K-tile.  acc = mfma(B,A): lane holds (m = rb*16+l15,
// n = cb*16+4g+r) -> vector C-stores.
#define GLD(gsrc, loff)                                                        \
    __builtin_amdgcn_global_load_lds(                                          \
        (const __attribute__((address_space(1))) void*)(gsrc),                 \
        (__attribute__((address_space(3))) void*)(smem + (loff)), 16, 0, 0)

__global__ __launch_bounds__(256)
void gemm_mfma_kernel(const __hip_bfloat16* __restrict__ A,
                      const __hip_bfloat16* __restrict__ Bt,
                      const float* __restrict__ bias,
                      void* __restrict__ Cv, int ldc, int obf, int nx)
{
    __shared__ __align__(16) char smem[32768];   // [2] x (A 8KB | B 8KB)

    // bijective XCD swizzle: gridDim.x divisible by 8
    const int cpx = gridDim.x >> 3;
    const int bid = blockIdx.x;
    const int bs  = (bid & 7) * cpx + (bid >> 3);
    const int n0  = (bs % nx) * 128;
    const int m0  = (bs / nx) * 128;

    const int tid = threadIdx.x;
    const int lane = tid & 63, wv = tid >> 6;
    const int wm = (wv >> 1) << 6, wn = (wv & 1) << 6;
    const int l15 = lane & 15, g = lane >> 4;

    const int srow = wv * 32 + (lane >> 2);
    const int scol = (lane & 3) << 3;
    const short* Ag = (const short*)A + (size_t)(m0 + srow) * 256 + scol;
    const short* Bg = (const short*)Bt + (size_t)(n0 + srow) * 256 + scol;

    f32x4 acc[4][4];
    const f32x4 z4 = {0.f, 0.f, 0.f, 0.f};
#pragma unroll
    for (int i = 0; i < 4; ++i)
#pragma unroll
        for (int j = 0; j < 4; ++j) acc[i][j] = z4;

    auto stage = [&](int buf, int k0) {
        const int b0 = buf * 16384 + wv * 2048;
        GLD(Ag + k0,            b0);
        GLD(Ag + k0 + 16 * 256, b0 + 1024);
        GLD(Bg + k0,            b0 + 8192);
        GLD(Bg + k0 + 16 * 256, b0 + 8192 + 1024);
    };

    stage(0, 0);
    __syncthreads();                       // tile 0 landed (implicit vmcnt(0))
    int cur = 0;
    for (int kt = 0; kt < 8; ++kt) {
        if (kt < 7) stage(cur ^ 1, (kt + 1) * 32);   // next tile in flight
        const char* Ab = smem + cur * 16384;
        const char* Bb = Ab + 8192;
        bf16x8 af[4], bfr[4];
#pragma unroll
        for (int rb = 0; rb < 4; ++rb)
            af[rb] = *(const bf16x8*)(Ab + (wm + rb * 16 + l15) * 64 + g * 16);
#pragma unroll
        for (int cb = 0; cb < 4; ++cb)
            bfr[cb] = *(const bf16x8*)(Bb + (wn + cb * 16 + l15) * 64 + g * 16);
#pragma unroll
        for (int rb = 0; rb < 4; ++rb)
#pragma unroll
            for (int cb = 0; cb < 4; ++cb)
                acc[rb][cb] = __builtin_amdgcn_mfma_f32_16x16x32_bf16(
                    bfr[cb], af[rb], acc[rb][cb], 0, 0, 0);   // swapped: N rows
        __syncthreads();                   // drains stage; frees buf cur
        cur ^= 1;
    }

    // epilogue: lane owns m = rb*16+l15 (per rb), n = cb*16+4g..+3 (per cb)
    float4 b4[4];
#pragma unroll
    for (int cb = 0; cb < 4; ++cb)
        b4[cb] = *(const float4*)(bias + n0 + wn + cb * 16 + (g << 2));
    if (obf) {
        __hip_bfloat16* C = (__hip_bfloat16*)Cv;
#pragma unroll
        for (int rb = 0; rb < 4; ++rb) {
            const int m = m0 + wm + rb * 16 + l15;
            __hip_bfloat16* crow = C + (size_t)m * ldc + n0 + wn + (g << 2);
#pragma unroll
            for (int cb = 0; cb < 4; ++cb) {
                u32x2 pk;
                pk[0] = pack2(acc[rb][cb][0] + b4[cb].x, acc[rb][cb][1] + b4[cb].y);
                pk[1] = pack2(acc[rb][cb][2] + b4[cb].z, acc[rb][cb][3] + b4[cb].w);
                *(u32x2*)(crow + cb * 16) = pk;
            }
        }
    } else {
        float* C = (float*)Cv;
#pragma unroll
        for (int rb = 0; rb < 4; ++rb) {
            const int m = m0 + wm + rb * 16 + l15;
            float* crow = C + (size_t)m * ldc + n0 + wn + (g << 2);
#pragma unroll
            for (int cb = 0; cb < 4; ++cb) {
                float4 o;
                o.x = acc[rb][cb][0] + b4[cb].x;
                o.y = acc[rb][cb][1] + b4[cb].y;
                o.z = acc[rb][cb][2] + b4[cb].z;
                o.w = acc[rb][cb][3] + b4[cb].w;
                *(float4*)(crow + cb * 16) = o;
            }
        }
    }
}

// ---------------- MFMA attention (bf16 in / bf16 out) — unchanged r9 -------
#define VT_OFF   0
#define KL_OFF   24576
#define SMAX_OFF 49152
#define SSUM_OFF 50176
#define GMAX_OFF 51200
#define PBUF_OFF 24576
#define ORED_OFF 0
#define LDS_SZ   51456

__global__ __launch_bounds__(256)
void attn_kernel(const __hip_bfloat16* __restrict__ qkvb,   // [25088][768]
                 const __hip_bfloat16* __restrict__ pool0b, // [512*12544]
                 const __hip_bfloat16* __restrict__ kv1b,   // [25088][512]
                 const __hip_bfloat16* __restrict__ kv2b,   // [12800][512]
                 const __hip_bfloat16* __restrict__ kv3b,   // [4608][512]
                 __hip_bfloat16* __restrict__ outb)         // [25088][256]
{
    __shared__ __align__(16) char smem[LDS_SZ];

    const int bid = blockIdx.x;
    const int wh  = (bid & 7) * 512 + (bid >> 3);
    const int win = wh >> 3, h = wh & 7;
    const int bb  = win >> 8, wi = (win >> 4) & 15, wj = win & 15;
    const int tid = threadIdx.x;
    const int lane = tid & 63, ww = tid >> 6;
    const int l15 = lane & 15, g = lane >> 4;
    const short* qkv = (const short*)qkvb;

    bf16x8 aq[4];
    const bf16x8 zb = {0, 0, 0, 0, 0, 0, 0, 0};
#pragma unroll
    for (int rb = 0; rb < 4; ++rb) {
        const int r16 = rb * 16 + l15;
        if (r16 < 49) {
            const int aa = r16 / 7, cc = r16 % 7;
            const int row = (bb * 112 + wi * 7 + aa) * 112 + wj * 7 + cc;
            aq[rb] = *(const bf16x8*)(qkv + (size_t)row * 768 + h * 32 + g * 8);
        } else aq[rb] = zb;
    }

    if (tid < 192) {
        const int j0   = tid * 2;
        const int gw   = j0 / 96, rem = j0 % 96;
        const int gk   = rem / 32, gl = (rem % 32) >> 1;
        const int keyA = (gw * 6 + gk * 2) * 16 + gl;
        u16x8 vb[2][4];
#pragma unroll
        for (int s = 0; s < 2; ++s) {
            const int key = keyA + s * 16;
            if (key < NKEYS) {
                const short *kp, *vp;
                if (key < 245) {
                    int aa, cc, hh, ww2;
                    if (key < 49) {
                        aa = key / 7; cc = key % 7;
                        hh = wi * 7 + aa; ww2 = wj * 7 + cc;
                    } else {
                        const int u = key - 49, si = u / 49, rr = u % 49;
                        aa = rr / 7; cc = rr % 7;
                        const int sh = (si < 2) ? -3 : 3;
                        const int sw = (si & 1) ? 3 : -3;
                        hh  = (wi * 7 + aa - sh + 112) % 112;
                        ww2 = (wj * 7 + cc - sw + 112) % 112;
                    }
                    const int row = (bb * 112 + hh) * 112 + ww2;
                    kp = qkv + (size_t)row * 768 + 256 + h * 32;
                    vp = qkv + (size_t)row * 768 + 512 + h * 32;
                } else if (key < 294) {
                    const short* p = (const short*)pool0b + (size_t)win * 12544 + h * 1568 + (key - 245) * 32;
                    kp = p; vp = p;
                } else if (key < 343) {
                    const short* p = (const short*)kv1b + (size_t)(win * 49 + key - 294) * 512 + h * 32;
                    kp = p; vp = p + 256;
                } else if (key < 368) {
                    const short* p = (const short*)kv2b + (size_t)(win * 25 + key - 343) * 512 + h * 32;
                    kp = p; vp = p + 256;
                } else {
                    const short* p = (const short*)kv3b + (size_t)(win * 9 + key - 368) * 512 + h * 32;
                    kp = p; vp = p + 256;
                }
                const u16x8* kp4 = (const u16x8*)kp;
                const u16x8* vp4 = (const u16x8*)vp;
#pragma unroll
                for (int jq = 0; jq < 4; ++jq)
                    *(u16x8*)(smem + KL_OFF + jq * 6144 + key * 16) = kp4[jq];
#pragma unroll
                for (int jq = 0; jq < 4; ++jq) vb[s][jq] = vp4[jq];
            } else {
                const u16x8 z = {0, 0, 0, 0, 0, 0, 0, 0};
#pragma unroll
                for (int jq = 0; jq < 4; ++jq)
                    *(u16x8*)(smem + KL_OFF + jq * 6144 + key * 16) = z;
#pragma unroll
                for (int jq = 0; jq < 4; ++jq) vb[s][jq] = z;
            }
        }
#pragma unroll
        for (int d = 0; d < 32; ++d) {
            int byte = d * 768 + tid * 4;
            byte ^= (d & 7) << 4;
            const u32 lo = vb[0][d >> 3][d & 7];
            const u32 hi = vb[1][d >> 3][d & 7];
            *(u32*)(smem + VT_OFF + byte) = lo | (hi << 16);
        }
    }
    __syncthreads();   // B0

    f32x4 S[4][6];
    const f32x4 z4 = {0.f, 0.f, 0.f, 0.f};
#pragma unroll
    for (int c = 0; c < 6; ++c) {
        const int key = (ww * 6 + c) * 16 + l15;
        const bf16x8 bk = *(const bf16x8*)(smem + KL_OFF + g * 6144 + key * 16);
#pragma unroll
        for (int rb = 0; rb < 4; ++rb)
            S[rb][c] = __builtin_amdgcn_mfma_f32_16x16x32_bf16(aq[rb], bk, z4, 0, 0, 0);
    }

    float mx[4][4];
#pragma unroll
    for (int rb = 0; rb < 4; ++rb)
#pragma unroll
        for (int r = 0; r < 4; ++r) {
            float v = S[rb][0][r];
#pragma unroll
            for (int c = 1; c < 6; ++c) v = fmaxf(v, S[rb][c][r]);
            mx[rb][r] = v;
        }
#pragma unroll
    for (int mvar = 1; mvar <= 8; mvar <<= 1)
#pragma unroll
        for (int rb = 0; rb < 4; ++rb)
#pragma unroll
            for (int r = 0; r < 4; ++r)
                mx[rb][r] = fmaxf(mx[rb][r], __shfl_xor(mx[rb][r], mvar, 64));
    {
        const int drb = l15 >> 2, dr = l15 & 3;
        const int row = 16 * drb + 4 * g + dr;
        *(float*)(smem + SMAX_OFF + (ww * 64 + row) * 4) = mx[drb][dr];
    }
    __syncthreads();   // B1

    if (tid < 64) {
        float gmv = *(const float*)(smem + SMAX_OFF + tid * 4);
#pragma unroll
        for (int wv2 = 1; wv2 < 4; ++wv2)
            gmv = fmaxf(gmv, *(const float*)(smem + SMAX_OFF + (wv2 * 64 + tid) * 4));
        *(float*)(smem + GMAX_OFF + tid * 4) = gmv;
    }
    __syncthreads();   // B2

    float gm[4][4];
#pragma unroll
    for (int rb = 0; rb < 4; ++rb)
#pragma unroll
        for (int r = 0; r < 4; ++r)
            gm[rb][r] = *(const float*)(smem + GMAX_OFF + (16 * rb + 4 * g + r) * 4);

    const float scale = 0.17677669529663687f;   // 32^-0.5
    float sm[4][4];
#pragma unroll
    for (int rb = 0; rb < 4; ++rb)
#pragma unroll
        for (int r = 0; r < 4; ++r) sm[rb][r] = 0.f;

#pragma unroll
    for (int c = 0; c < 6; ++c) {
        const bool tail = (ww == 3) && (c == 5) && (l15 >= 9);   // keys >= 377
#pragma unroll
        for (int rb = 0; rb < 4; ++rb) {
            f32x4 p;
#pragma unroll
            for (int r = 0; r < 4; ++r) {
                const float e = tail ? 0.f : __expf((S[rb][c][r] - gm[rb][r]) * scale);
                p[r] = e;
                sm[rb][r] += e;
            }
            S[rb][c] = p;
        }
    }
#pragma unroll
    for (int mvar = 1; mvar <= 8; mvar <<= 1)
#pragma unroll
        for (int rb = 0; rb < 4; ++rb)
#pragma unroll
            for (int r = 0; r < 4; ++r)
                sm[rb][r] += __shfl_xor(sm[rb][r], mvar, 64);
    {
        const int drb = l15 >> 2, dr = l15 & 3;
        const int row = 16 * drb + 4 * g + dr;
        *(float*)(smem + SSUM_OFF + (ww * 64 + row) * 4) = sm[drb][dr];
    }

    f32x4 O_[4][2];
#pragma unroll
    for (int rb = 0; rb < 4; ++rb) { O_[rb][0] = z4; O_[rb][1] = z4; }

    char* pbuf = smem + PBUF_OFF + ww * 5120;
#pragma unroll
    for (int kcl = 0; kcl < 3; ++kcl) {
#pragma unroll
        for (int rb = 0; rb < 4; ++rb)
#pragma unroll
            for (int r = 0; r < 4; ++r) {
                const int row = 16 * rb + 4 * g + r;
                *(u32*)(pbuf + row * 80 + l15 * 4) =
                    pack2(S[rb][2 * kcl][r], S[rb][2 * kcl + 1][r]);
            }
        bf16x8 bv[2];
#pragma unroll
        for (int nc = 0; nc < 2; ++nc) {
            const int dim = 16 * nc + l15;
            int byte = dim * 768 + ww * 192 + kcl * 64 + g * 16;
            byte ^= (dim & 7) << 4;
            bv[nc] = *(const bf16x8*)(smem + VT_OFF + byte);
        }
#pragma unroll
        for (int rb = 0; rb < 4; ++rb) {
            const bf16x8 ap = *(const bf16x8*)(pbuf + (16 * rb + l15) * 80 + g * 16);
            O_[rb][0] = __builtin_amdgcn_mfma_f32_16x16x32_bf16(ap, bv[0], O_[rb][0], 0, 0, 0);
            O_[rb][1] = __builtin_amdgcn_mfma_f32_16x16x32_bf16(ap, bv[1], O_[rb][1], 0, 0, 0);
        }
    }
    __syncthreads();   // B3

#pragma unroll
    for (int rb = 0; rb < 4; ++rb)
#pragma unroll
        for (int nc = 0; nc < 2; ++nc)
#pragma unroll
            for (int r = 0; r < 4; ++r) {
                const int row = 16 * rb + 4 * g + r;
                const int col = 16 * nc + l15;
                *(float*)(smem + ORED_OFF + ((ww * 64 + row) * 33 + col) * 4) = O_[rb][nc][r];
            }
    __syncthreads();   // B4

    {
        const int row = tid >> 2, d0 = (tid & 3) * 8;
        if (row < 49) {
            float lt = 0.f;
#pragma unroll
            for (int wv2 = 0; wv2 < 4; ++wv2)
                lt += *(const float*)(smem + SSUM_OFF + (wv2 * 64 + row) * 4);
            const float inv = 1.0f / lt;
            float o[8];
#pragma unroll
            for (int i = 0; i < 8; ++i) {
                float s = 0.f;
#pragma unroll
                for (int wv2 = 0; wv2 < 4; ++wv2)
                    s += *(const float*)(smem + ORED_OFF + ((wv2 * 64 + row) * 33 + d0 + i) * 4);
                o[i] = s * inv;
            }
            u32x4 pk;
#pragma unroll
            for (int i = 0; i < 4; ++i) pk[i] = pack2(o[2 * i], o[2 * i + 1]);
            *(u32x4*)((short*)outb + (size_t)(win * 49 + row) * 256 + h * 32 + d0) = pk;
        }
    }
}

// ---------------- launch ----------------
extern "C" void kernel_launch(void* const* d_in, const int* in_sizes, int n_in,
                              void* d_out, int out_size, void* d_ws, size_t ws_size,
                              hipStream_t stream)
{
    const float* x      = (const float*)d_in[0];
    const float* pool0  = (const float*)d_in[1];
    const float* clip1  = (const float*)d_in[2];
    const float* clip2  = (const float*)d_in[3];
    const float* clip3  = (const float*)d_in[4];
    const float* qkv_w  = (const float*)d_in[5];
    const float* qkv_b  = (const float*)d_in[6];
    const float* proj_w = (const float*)d_in[7];
    const float* proj_b = (const float*)d_in[8];
    float* out = (float*)d_out;

    __hip_bfloat16* ws  = (__hip_bfloat16*)d_ws;
    __hip_bfloat16* qkvb = ws;                          // 25088*768
    __hip_bfloat16* kv1b = qkvb + 25088ull * 768;       // 25088*512
    __hip_bfloat16* kv2b = kv1b + 25088ull * 512;       // 12800*512
    __hip_bfloat16* kv3b = kv2b + 12800ull * 512;       //  4608*512
    __hip_bfloat16* attnb = kv3b + 4608ull * 512;       // 25088*256
    __hip_bfloat16* xb   = attnb + 25088ull * 256;      // 25088*256
    __hip_bfloat16* c1b  = xb + 25088ull * 256;         // 25088*256
    __hip_bfloat16* c2b  = c1b + 25088ull * 256;        // 12800*256
    __hip_bfloat16* c3b  = c2b + 12800ull * 256;        //  4608*256
    __hip_bfloat16* p0b  = c3b + 4608ull * 256;         // 512*12544
    __hip_bfloat16* wq   = p0b + 512ull * 12544;        // 768*256
    __hip_bfloat16* wp   = wq + 768ull * 256;           // 256*256

    cvt_kernel<<<dim3(2048), dim3(256), 0, stream>>>(
        x, clip1, clip2, clip3, pool0, xb, c1b, c2b, c3b, p0b);
    wprep_kernel<<<dim3(1024), dim3(256), 0, stream>>>(qkv_w, proj_w, wq, wp);

    // x -> qkv (bf16 out): 6 x 196 = 1176 blocks (%8==0)
    gemm_mfma_kernel<<<dim3(1176), dim3(256), 0, stream>>>(
        xb, wq, qkv_b, qkvb, 768, 1, 6);
    // clips -> k|v (bf16 out): fused M=42496 -> 4 x 332 = 1328 blocks (%8==0)
    gemm_mfma_kernel<<<dim3(1328), dim3(256), 0, stream>>>(
        c1b, wq + 256 * 256, qkv_b + 256, kv1b, 512, 1, 4);
    // attention (bf16 in/out), XCD-chunked
    attn_kernel<<<dim3(512 * 8), dim3(256), 0, stream>>>(
        qkvb, p0b, kv1b, kv2b, kv3b, attnb);
    // projection (fp32 out): 2 x 196 = 392 blocks (%8==0)
    gemm_mfma_kernel<<<dim3(392), dim3(256), 0, stream>>>(
        attnb, wp, proj_b, out, 256, 0, 2);
}

// Round 11
// 295.388 us; speedup vs baseline: 1.0142x; 1.0142x over previous
//
#include <hip/hip_runtime.h>
#include <hip/hip_bf16.h>

// CffmTransformerBlock3d3 — round 11 (instrumentation + fusion).
//  * cvtw  : cvt(all fp32 acts -> bf16) + weight transpose fused, one launch.
//  * GEMM  : qkv-GEMM and clip-GEMM fused into one 2504-block launch
//            (segment decoded from swizzled block id). Interior identical r10.
//  * attn  : split into 2 x 2048-block launches (halves dispatch duration so
//            GEMM/cvt dispatches surface in rocprof top-5). Math identical.

#define NKEYS 377

typedef unsigned int u32;
typedef unsigned short u16;
typedef __attribute__((ext_vector_type(8))) short bf16x8;
typedef __attribute__((ext_vector_type(8))) unsigned short u16x8;
typedef __attribute__((ext_vector_type(4))) unsigned int u32x4;
typedef __attribute__((ext_vector_type(2))) unsigned int u32x2;
typedef __attribute__((ext_vector_type(4))) float f32x4;

__device__ __forceinline__ u16 f2bf(float f) {
    u32 b = __float_as_uint(f);
    b += 0x7FFFu + ((b >> 16) & 1u);
    return (u16)(b >> 16);
}
__device__ __forceinline__ u32 pack2(float lo, float hi) {
    return (u32)f2bf(lo) | ((u32)f2bf(hi) << 16);
}
__device__ __forceinline__ bf16x8 cvt8(float4 x, float4 y) {
    union { bf16x8 v; __hip_bfloat162 h[4]; } un;
    un.h[0] = __float22bfloat162_rn(make_float2(x.x, x.y));
    un.h[1] = __float22bfloat162_rn(make_float2(x.z, x.w));
    un.h[2] = __float22bfloat162_rn(make_float2(y.x, y.y));
    un.h[3] = __float22bfloat162_rn(make_float2(y.z, y.w));
    return un.v;
}

// -------- fused fp32->bf16 activation cvt + weight transpose/convert --------
__global__ __launch_bounds__(256)
void cvtw_kernel(const float* __restrict__ x,  const float* __restrict__ c1,
                 const float* __restrict__ c2, const float* __restrict__ c3,
                 const float* __restrict__ p0,
                 const float* __restrict__ qkv_w, const float* __restrict__ proj_w,
                 __hip_bfloat16* __restrict__ xb, __hip_bfloat16* __restrict__ c1b,
                 __hip_bfloat16* __restrict__ c2b, __hip_bfloat16* __restrict__ c3b,
                 __hip_bfloat16* __restrict__ p0b,
                 __hip_bfloat16* __restrict__ wq, __hip_bfloat16* __restrict__ wp)
{
    const int U0 = 802816, U1 = 1605632, U2 = 2015232, U3 = 2162688, U4 = 2965504;
    for (int u = blockIdx.x * 256 + threadIdx.x; u < U4; u += gridDim.x * 256) {
        const float* s; __hip_bfloat16* d; int o;
        if (u < U0)      { s = x;  d = xb;  o = u; }
        else if (u < U1) { s = c1; d = c1b; o = u - U0; }
        else if (u < U2) { s = c2; d = c2b; o = u - U1; }
        else if (u < U3) { s = c3; d = c3b; o = u - U2; }
        else             { s = p0; d = p0b; o = u - U3; }
        const float4 a = *(const float4*)(s + (size_t)o * 8);
        const float4 b = *(const float4*)(s + (size_t)o * 8 + 4);
        *(bf16x8*)((short*)d + (size_t)o * 8) = cvt8(a, b);
    }
    // weight transpose: Wt[n][k] = bf16(W[k][n]); 262144 scalar units
    for (int u = blockIdx.x * 256 + threadIdx.x; u < 262144; u += gridDim.x * 256) {
        const int n = u >> 8, k = u & 255;
        if (n < 768) wq[n * 256 + k] = __float2bfloat16(qkv_w[k * 768 + n]);
        else         wp[(n - 768) * 256 + k] = __float2bfloat16(proj_w[k * 256 + (n - 768)]);
    }
}

// ---------------- bf16 MFMA GEMM tile body (r10 interior) ----------------
#define GLD(gsrc, loff)                                                        \
    __builtin_amdgcn_global_load_lds(                                          \
        (const __attribute__((address_space(1))) void*)(gsrc),                 \
        (__attribute__((address_space(3))) void*)(smem + (loff)), 16, 0, 0)

__device__ __forceinline__
void gemm_tile(const __hip_bfloat16* __restrict__ A,
               const __hip_bfloat16* __restrict__ Bt,
               const float* __restrict__ bias,
               void* __restrict__ Cv, int ldc, int obf,
               int m0, int n0, char* smem)
{
    const int tid = threadIdx.x;
    const int lane = tid & 63, wv = tid >> 6;
    const int wm = (wv >> 1) << 6, wn = (wv & 1) << 6;
    const int l15 = lane & 15, g = lane >> 4;

    const int srow = wv * 32 + (lane >> 2);
    const int scol = (lane & 3) << 3;
    const short* Ag = (const short*)A + (size_t)(m0 + srow) * 256 + scol;
    const short* Bg = (const short*)Bt + (size_t)(n0 + srow) * 256 + scol;

    f32x4 acc[4][4];
    const f32x4 z4 = {0.f, 0.f, 0.f, 0.f};
#pragma unroll
    for (int i = 0; i < 4; ++i)
#pragma unroll
        for (int j = 0; j < 4; ++j) acc[i][j] = z4;

    auto stage = [&](int buf, int k0) {
        const int b0 = buf * 16384 + wv * 2048;
        GLD(Ag + k0,            b0);
        GLD(Ag + k0 + 16 * 256, b0 + 1024);
        GLD(Bg + k0,            b0 + 8192);
        GLD(Bg + k0 + 16 * 256, b0 + 8192 + 1024);
    };

    stage(0, 0);
    __syncthreads();                       // tile 0 landed (implicit vmcnt(0))
    int cur = 0;
    for (int kt = 0; kt < 8; ++kt) {
        if (kt < 7) stage(cur ^ 1, (kt + 1) * 32);   // next tile in flight
        const char* Ab = smem + cur * 16384;
        const char* Bb = Ab + 8192;
        bf16x8 af[4], bfr[4];
#pragma unroll
        for (int rb = 0; rb < 4; ++rb)
            af[rb] = *(const bf16x8*)(Ab + (wm + rb * 16 + l15) * 64 + g * 16);
#pragma unroll
        for (int cb = 0; cb < 4; ++cb)
            bfr[cb] = *(const bf16x8*)(Bb + (wn + cb * 16 + l15) * 64 + g * 16);
#pragma unroll
        for (int rb = 0; rb < 4; ++rb)
#pragma unroll
            for (int cb = 0; cb < 4; ++cb)
                acc[rb][cb] = __builtin_amdgcn_mfma_f32_16x16x32_bf16(
                    bfr[cb], af[rb], acc[rb][cb], 0, 0, 0);   // swapped: N rows
        __syncthreads();
        cur ^= 1;
    }

    float4 b4[4];
#pragma unroll
    for (int cb = 0; cb < 4; ++cb)
        b4[cb] = *(const float4*)(bias + n0 + wn + cb * 16 + (g << 2));
    if (obf) {
        __hip_bfloat16* C = (__hip_bfloat16*)Cv;
#pragma unroll
        for (int rb = 0; rb < 4; ++rb) {
            const int m = m0 + wm + rb * 16 + l15;
            __hip_bfloat16* crow = C + (size_t)m * ldc + n0 + wn + (g << 2);
#pragma unroll
            for (int cb = 0; cb < 4; ++cb) {
                u32x2 pk;
                pk[0] = pack2(acc[rb][cb][0] + b4[cb].x, acc[rb][cb][1] + b4[cb].y);
                pk[1] = pack2(acc[rb][cb][2] + b4[cb].z, acc[rb][cb][3] + b4[cb].w);
                *(u32x2*)(crow + cb * 16) = pk;
            }
        }
    } else {
        float* C = (float*)Cv;
#pragma unroll
        for (int rb = 0; rb < 4; ++rb) {
            const int m = m0 + wm + rb * 16 + l15;
            float* crow = C + (size_t)m * ldc + n0 + wn + (g << 2);
#pragma unroll
            for (int cb = 0; cb < 4; ++cb) {
                float4 o;
                o.x = acc[rb][cb][0] + b4[cb].x;
                o.y = acc[rb][cb][1] + b4[cb].y;
                o.z = acc[rb][cb][2] + b4[cb].z;
                o.w = acc[rb][cb][3] + b4[cb].w;
                *(float4*)(crow + cb * 16) = o;
            }
        }
    }
}

// fused qkv + clip GEMM: blocks [0,1176) -> x@wq (N=768); [1176,2504) -> clips
__global__ __launch_bounds__(256)
void gemm_fused_kernel(const __hip_bfloat16* __restrict__ xb,
                       const __hip_bfloat16* __restrict__ c1b,
                       const __hip_bfloat16* __restrict__ wq,
                       const float* __restrict__ qkv_b,
                       __hip_bfloat16* __restrict__ qkvb,
                       __hip_bfloat16* __restrict__ kv1b)
{
    __shared__ __align__(16) char smem[32768];
    const int cpx = gridDim.x >> 3;               // 313
    const int bid = blockIdx.x;
    const int bs  = (bid & 7) * cpx + (bid >> 3); // bijective, 2504 % 8 == 0
    if (bs < 1176) {
        gemm_tile(xb, wq, qkv_b, qkvb, 768, 1,
                  (bs / 6) * 128, (bs % 6) * 128, smem);
    } else {
        const int b2 = bs - 1176;
        gemm_tile(c1b, wq + 256 * 256, qkv_b + 256, kv1b, 512, 1,
                  (b2 / 4) * 128, (b2 % 4) * 128, smem);
    }
}

// standalone GEMM (proj)
__global__ __launch_bounds__(256)
void gemm_mfma_kernel(const __hip_bfloat16* __restrict__ A,
                      const __hip_bfloat16* __restrict__ Bt,
                      const float* __restrict__ bias,
                      void* __restrict__ Cv, int ldc, int obf, int nx)
{
    __shared__ __align__(16) char smem[32768];
    const int cpx = gridDim.x >> 3;
    const int bid = blockIdx.x;
    const int bs  = (bid & 7) * cpx + (bid >> 3);
    gemm_tile(A, Bt, bias, Cv, ldc, obf, (bs / nx) * 128, (bs % nx) * 128, smem);
}

// ---------------- MFMA attention (bf16 in / bf16 out) — r9 math ------------
#define VT_OFF   0
#define KL_OFF   24576
#define SMAX_OFF 49152
#define SSUM_OFF 50176
#define GMAX_OFF 51200
#define PBUF_OFF 24576
#define ORED_OFF 0
#define LDS_SZ   51456

__global__ __launch_bounds__(256)
void attn_kernel(const __hip_bfloat16* __restrict__ qkvb,   // [25088][768]
                 const __hip_bfloat16* __restrict__ pool0b, // [512*12544]
                 const __hip_bfloat16* __restrict__ kv1b,   // [25088][512]
                 const __hip_bfloat16* __restrict__ kv2b,   // [12800][512]
                 const __hip_bfloat16* __restrict__ kv3b,   // [4608][512]
                 __hip_bfloat16* __restrict__ outb,         // [25088][256]
                 int whbase)
{
    __shared__ __align__(16) char smem[LDS_SZ];

    // per-launch bijective XCD chunking (gridDim 2048): 256 wh per XCD chunk
    const int bid = blockIdx.x;
    const int wh  = whbase + ((bid & 7) << 8) + (bid >> 3);
    const int win = wh >> 3, h = wh & 7;
    const int bb  = win >> 8, wi = (win >> 4) & 15, wj = win & 15;
    const int tid = threadIdx.x;
    const int lane = tid & 63, ww = tid >> 6;
    const int l15 = lane & 15, g = lane >> 4;
    const short* qkv = (const short*)qkvb;

    bf16x8 aq[4];
    const bf16x8 zb = {0, 0, 0, 0, 0, 0, 0, 0};
#pragma unroll
    for (int rb = 0; rb < 4; ++rb) {
        const int r16 = rb * 16 + l15;
        if (r16 < 49) {
            const int aa = r16 / 7, cc = r16 % 7;
            const int row = (bb * 112 + wi * 7 + aa) * 112 + wj * 7 + cc;
            aq[rb] = *(const bf16x8*)(qkv + (size_t)row * 768 + h * 32 + g * 8);
        } else aq[rb] = zb;
    }

    if (tid < 192) {
        const int j0   = tid * 2;
        const int gw   = j0 / 96, rem = j0 % 96;
        const int gk   = rem / 32, gl = (rem % 32) >> 1;
        const int keyA = (gw * 6 + gk * 2) * 16 + gl;
        u16x8 vb[2][4];
#pragma unroll
        for (int s = 0; s < 2; ++s) {
            const int key = keyA + s * 16;
            if (key < NKEYS) {
                const short *kp, *vp;
                if (key < 245) {
                    int aa, cc, hh, ww2;
                    if (key < 49) {
                        aa = key / 7; cc = key % 7;
                        hh = wi * 7 + aa; ww2 = wj * 7 + cc;
                    } else {
                        const int u = key - 49, si = u / 49, rr = u % 49;
                        aa = rr / 7; cc = rr % 7;
                        const int sh = (si < 2) ? -3 : 3;
                        const int sw = (si & 1) ? 3 : -3;
                        hh  = (wi * 7 + aa - sh + 112) % 112;
                        ww2 = (wj * 7 + cc - sw + 112) % 112;
                    }
                    const int row = (bb * 112 + hh) * 112 + ww2;
                    kp = qkv + (size_t)row * 768 + 256 + h * 32;
                    vp = qkv + (size_t)row * 768 + 512 + h * 32;
                } else if (key < 294) {
                    const short* p = (const short*)pool0b + (size_t)win * 12544 + h * 1568 + (key - 245) * 32;
                    kp = p; vp = p;
                } else if (key < 343) {
                    const short* p = (const short*)kv1b + (size_t)(win * 49 + key - 294) * 512 + h * 32;
                    kp = p; vp = p + 256;
                } else if (key < 368) {
                    const short* p = (const short*)kv2b + (size_t)(win * 25 + key - 343) * 512 + h * 32;
                    kp = p; vp = p + 256;
                } else {
                    const short* p = (const short*)kv3b + (size_t)(win * 9 + key - 368) * 512 + h * 32;
                    kp = p; vp = p + 256;
                }
                const u16x8* kp4 = (const u16x8*)kp;
                const u16x8* vp4 = (const u16x8*)vp;
#pragma unroll
                for (int jq = 0; jq < 4; ++jq)
                    *(u16x8*)(smem + KL_OFF + jq * 6144 + key * 16) = kp4[jq];
#pragma unroll
                for (int jq = 0; jq < 4; ++jq) vb[s][jq] = vp4[jq];
            } else {
                const u16x8 z = {0, 0, 0, 0, 0, 0, 0, 0};
#pragma unroll
                for (int jq = 0; jq < 4; ++jq)
                    *(u16x8*)(smem + KL_OFF + jq * 6144 + key * 16) = z;
#pragma unroll
                for (int jq = 0; jq < 4; ++jq) vb[s][jq] = z;
            }
        }
#pragma unroll
        for (int d = 0; d < 32; ++d) {
            int byte = d * 768 + tid * 4;
            byte ^= (d & 7) << 4;
            const u32 lo = vb[0][d >> 3][d & 7];
            const u32 hi = vb[1][d >> 3][d & 7];
            *(u32*)(smem + VT_OFF + byte) = lo | (hi << 16);
        }
    }
    __syncthreads();   // B0

    f32x4 S[4][6];
    const f32x4 z4 = {0.f, 0.f, 0.f, 0.f};
#pragma unroll
    for (int c = 0; c < 6; ++c) {
        const int key = (ww * 6 + c) * 16 + l15;
        const bf16x8 bk = *(const bf16x8*)(smem + KL_OFF + g * 6144 + key * 16);
#pragma unroll
        for (int rb = 0; rb < 4; ++rb)
            S[rb][c] = __builtin_amdgcn_mfma_f32_16x16x32_bf16(aq[rb], bk, z4, 0, 0, 0);
    }

    float mx[4][4];
#pragma unroll
    for (int rb = 0; rb < 4; ++rb)
#pragma unroll
        for (int r = 0; r < 4; ++r) {
            float v = S[rb][0][r];
#pragma unroll
            for (int c = 1; c < 6; ++c) v = fmaxf(v, S[rb][c][r]);
            mx[rb][r] = v;
        }
#pragma unroll
    for (int mvar = 1; mvar <= 8; mvar <<= 1)
#pragma unroll
        for (int rb = 0; rb < 4; ++rb)
#pragma unroll
            for (int r = 0; r < 4; ++r)
                mx[rb][r] = fmaxf(mx[rb][r], __shfl_xor(mx[rb][r], mvar, 64));
    {
        const int drb = l15 >> 2, dr = l15 & 3;
        const int row = 16 * drb + 4 * g + dr;
        *(float*)(smem + SMAX_OFF + (ww * 64 + row) * 4) = mx[drb][dr];
    }
    __syncthreads();   // B1

    if (tid < 64) {
        float gmv = *(const float*)(smem + SMAX_OFF + tid * 4);
#pragma unroll
        for (int wv2 = 1; wv2 < 4; ++wv2)
            gmv = fmaxf(gmv, *(const float*)(smem + SMAX_OFF + (wv2 * 64 + tid) * 4));
        *(float*)(smem + GMAX_OFF + tid * 4) = gmv;
    }
    __syncthreads();   // B2

    float gm[4][4];
#pragma unroll
    for (int rb = 0; rb < 4; ++rb)
#pragma unroll
        for (int r = 0; r < 4; ++r)
            gm[rb][r] = *(const float*)(smem + GMAX_OFF + (16 * rb + 4 * g + r) * 4);

    const float scale = 0.17677669529663687f;   // 32^-0.5
    float sm[4][4];
#pragma unroll
    for (int rb = 0; rb < 4; ++rb)
#pragma unroll
        for (int r = 0; r < 4; ++r) sm[rb][r] = 0.f;

#pragma unroll
    for (int c = 0; c < 6; ++c) {
        const bool tail = (ww == 3) && (c == 5) && (l15 >= 9);   // keys >= 377
#pragma unroll
        for (int rb = 0; rb < 4; ++rb) {
            f32x4 p;
#pragma unroll
            for (int r = 0; r < 4; ++r) {
                const float e = tail ? 0.f : __expf((S[rb][c][r] - gm[rb][r]) * scale);
                p[r] = e;
                sm[rb][r] += e;
            }
            S[rb][c] = p;
        }
    }
#pragma unroll
    for (int mvar = 1; mvar <= 8; mvar <<= 1)
#pragma unroll
        for (int rb = 0; rb < 4; ++rb)
#pragma unroll
            for (int r = 0; r < 4; ++r)
                sm[rb][r] += __shfl_xor(sm[rb][r], mvar, 64);
    {
        const int drb = l15 >> 2, dr = l15 & 3;
        const int row = 16 * drb + 4 * g + dr;
        *(float*)(smem + SSUM_OFF + (ww * 64 + row) * 4) = sm[drb][dr];
    }

    f32x4 O_[4][2];
#pragma unroll
    for (int rb = 0; rb < 4; ++rb) { O_[rb][0] = z4; O_[rb][1] = z4; }

    char* pbuf = smem + PBUF_OFF + ww * 5120;
#pragma unroll
    for (int kcl = 0; kcl < 3; ++kcl) {
#pragma unroll
        for (int rb = 0; rb < 4; ++rb)
#pragma unroll
            for (int r = 0; r < 4; ++r) {
                const int row = 16 * rb + 4 * g + r;
                *(u32*)(pbuf + row * 80 + l15 * 4) =
                    pack2(S[rb][2 * kcl][r], S[rb][2 * kcl + 1][r]);
            }
        bf16x8 bv[2];
#pragma unroll
        for (int nc = 0; nc < 2; ++nc) {
            const int dim = 16 * nc + l15;
            int byte = dim * 768 + ww * 192 + kcl * 64 + g * 16;
            byte ^= (dim & 7) << 4;
            bv[nc] = *(const bf16x8*)(smem + VT_OFF + byte);
        }
#pragma unroll
        for (int rb = 0; rb < 4; ++rb) {
            const bf16x8 ap = *(const bf16x8*)(pbuf + (16 * rb + l15) * 80 + g * 16);
            O_[rb][0] = __builtin_amdgcn_mfma_f32_16x16x32_bf16(ap, bv[0], O_[rb][0], 0, 0, 0);
            O_[rb][1] = __builtin_amdgcn_mfma_f32_16x16x32_bf16(ap, bv[1], O_[rb][1], 0, 0, 0);
        }
    }
    __syncthreads();   // B3

#pragma unroll
    for (int rb = 0; rb < 4; ++rb)
#pragma unroll
        for (int nc = 0; nc < 2; ++nc)
#pragma unroll
            for (int r = 0; r < 4; ++r) {
                const int row = 16 * rb + 4 * g + r;
                const int col = 16 * nc + l15;
                *(float*)(smem + ORED_OFF + ((ww * 64 + row) * 33 + col) * 4) = O_[rb][nc][r];
            }
    __syncthreads();   // B4

    {
        const int row = tid >> 2, d0 = (tid & 3) * 8;
        if (row < 49) {
            float lt = 0.f;
#pragma unroll
            for (int wv2 = 0; wv2 < 4; ++wv2)
                lt += *(const float*)(smem + SSUM_OFF + (wv2 * 64 + row) * 4);
            const float inv = 1.0f / lt;
            float o[8];
#pragma unroll
            for (int i = 0; i < 8; ++i) {
                float s = 0.f;
#pragma unroll
                for (int wv2 = 0; wv2 < 4; ++wv2)
                    s += *(const float*)(smem + ORED_OFF + ((wv2 * 64 + row) * 33 + d0 + i) * 4);
                o[i] = s * inv;
            }
            u32x4 pk;
#pragma unroll
            for (int i = 0; i < 4; ++i) pk[i] = pack2(o[2 * i], o[2 * i + 1]);
            *(u32x4*)((short*)outb + (size_t)(win * 49 + row) * 256 + h * 32 + d0) = pk;
        }
    }
}

// ---------------- launch ----------------
extern "C" void kernel_launch(void* const* d_in, const int* in_sizes, int n_in,
                              void* d_out, int out_size, void* d_ws, size_t ws_size,
                              hipStream_t stream)
{
    const float* x      = (const float*)d_in[0];
    const float* pool0  = (const float*)d_in[1];
    const float* clip1  = (const float*)d_in[2];
    const float* clip2  = (const float*)d_in[3];
    const float* clip3  = (const float*)d_in[4];
    const float* qkv_w  = (const float*)d_in[5];
    const float* qkv_b  = (const float*)d_in[6];
    const float* proj_w = (const float*)d_in[7];
    const float* proj_b = (const float*)d_in[8];
    float* out = (float*)d_out;

    __hip_bfloat16* ws  = (__hip_bfloat16*)d_ws;
    __hip_bfloat16* qkvb = ws;                          // 25088*768
    __hip_bfloat16* kv1b = qkvb + 25088ull * 768;       // 25088*512
    __hip_bfloat16* kv2b = kv1b + 25088ull * 512;       // 12800*512
    __hip_bfloat16* kv3b = kv2b + 12800ull * 512;       //  4608*512
    __hip_bfloat16* attnb = kv3b + 4608ull * 512;       // 25088*256
    __hip_bfloat16* xb   = attnb + 25088ull * 256;      // 25088*256
    __hip_bfloat16* c1b  = xb + 25088ull * 256;         // 25088*256
    __hip_bfloat16* c2b  = c1b + 25088ull * 256;        // 12800*256
    __hip_bfloat16* c3b  = c2b + 12800ull * 256;        //  4608*256
    __hip_bfloat16* p0b  = c3b + 4608ull * 256;         // 512*12544
    __hip_bfloat16* wq   = p0b + 512ull * 12544;        // 768*256
    __hip_bfloat16* wp   = wq + 768ull * 256;           // 256*256

    // 1) activations -> bf16 + weight transpose (fused)
    cvtw_kernel<<<dim3(2048), dim3(256), 0, stream>>>(
        x, clip1, clip2, clip3, pool0, qkv_w, proj_w,
        xb, c1b, c2b, c3b, p0b, wq, wp);

    // 2) fused qkv + clip GEMM: 1176 + 1328 = 2504 blocks (%8==0)
    gemm_fused_kernel<<<dim3(2504), dim3(256), 0, stream>>>(
        xb, c1b, wq, qkv_b, qkvb, kv1b);

    // 3) attention, split into two 2048-block launches (instrumentation)
    attn_kernel<<<dim3(2048), dim3(256), 0, stream>>>(
        qkvb, p0b, kv1b, kv2b, kv3b, attnb, 0);
    attn_kernel<<<dim3(2048), dim3(256), 0, stream>>>(
        qkvb, p0b, kv1b, kv2b, kv3b, attnb, 2048);

    // 4) projection (fp32 out): 392 blocks (%8==0)
    gemm_mfma_kernel<<<dim3(392), dim3(256), 0, stream>>>(
        attnb, wp, proj_b, out, 256, 0, 2);
}